// Round 8
// baseline (187.141 us; speedup 1.0000x reference)
//
#include <hip/hip_runtime.h>

#define DEV __device__ __forceinline__

// ---------------- constants ----------------
// N_NODES=32768, N_EDGES=65536, H=8, D=64, DS=63, M=128, R=H*N=262144
#define NNODES 32768
#define NEDGES 65536
#define NROWS  262144
#define EPSF   1e-7f
#define SQRT2F 1.4142135623730951f
#define LOG2E  1.4426950408889634f
#define LOG2SQRT63 2.9886399611087573f   // log2(sqrt(63))

// ---------------- ws layout (bytes) ----------------
#define OFF_WFRAG 0u          // bf16 [3][8][2][4][64][8]  W in MFMA B-frag order (196608 B) [dead after k2]
#define OFF_LASTB 0u          // bf8  [8][4][4][64][8] B-frag of last (65536 B) [written k35, read k4]
#define OFF_PFRAG 196608u     // bf16 [8][2][64][8]  sqrt(2)*log2e*P, A-frag order (pi-permuted m) (16384 B)
#define OFF_EA    212992u     // float [1] (zeroed by k01)
#define OFF_U     409600u     // bf16 [N][64] u (4194304 B) [dead after k2]
#define OFF_PART  42352640u   // bf8 e5m2 [256 c][8 h][64 d][128 m] split-K partials of last (16777216 B)
#define OFF_PHIQ  75907072u   // fp8 e4m3 [n][h][128] (33554432 B)
#define OFF_PHIK  143015936u  // fp8 e4m3 [n][h][128] (33554432 B)

typedef short s8v __attribute__((ext_vector_type(8)));   // 8 bf16 in 4 VGPRs (MFMA A/B frag)
typedef float f4v __attribute__((ext_vector_type(4)));   // MFMA C/D frag
typedef float f2v __attribute__((ext_vector_type(2)));

// ---------------- helpers ----------------
DEV unsigned short f2bf(float f) {  // rne
  unsigned u = __float_as_uint(f);
  return (unsigned short)((u + 0x7fffu + ((u >> 16) & 1u)) >> 16);
}
DEV float bf2f(unsigned short h) { return __uint_as_float(((unsigned)h) << 16); }
// pack two f32 -> two bf16 (round-half-up) in one uint: low short = bf16(lo), high = bf16(hi)
DEV unsigned pack2(float lo, float hi) {
  return __builtin_amdgcn_perm(__float_as_uint(hi) + 0x8000u, __float_as_uint(lo) + 0x8000u, 0x07060302u);
}
DEV float frcp(float x) { return __builtin_amdgcn_rcpf(x); }
DEV float fsqrt(float x) { return __builtin_amdgcn_sqrtf(x); }    // raw v_sqrt_f32, args in normal range
DEV float fexp2(float x) { return __builtin_amdgcn_exp2f(x); }    // raw v_exp_f32, args in normal range

// ---------------- K01: u cast (+ blocks<96: pack W/P frags; block0: zero ea) ----------------
// u = logmap0(proj(expmap0(z))) == [0, z[1:]] identically (acosh(cosh t)=t for t~0.08).
__global__ __launch_bounds__(256) void k01_prep(const float* __restrict__ z, unsigned short* __restrict__ ubf,
                                                const float* __restrict__ Wq, const float* __restrict__ Wk,
                                                const float* __restrict__ Wv, const float* __restrict__ P,
                                                unsigned short* __restrict__ Wfrag, unsigned short* __restrict__ Pfrag,
                                                float* __restrict__ ea) {
  int i = blockIdx.x * 256 + threadIdx.x;  // 524288 float4 groups
  float4 v = *(const float4*)(z + (size_t)i * 4);
  if ((i & 15) == 0) v.x = 0.f;  // time slot
  uint2 pk;
  pk.x = pack2(v.x, v.y);
  pk.y = pack2(v.z, v.w);
  *(uint2*)(ubf + (size_t)i * 4) = pk;

  if (blockIdx.x < 96) {
    if (i == 0) ea[0] = 0.f;
    int stride = 96 * 256;
    // Wfrag[sm][h][ks][nt][lane][j] : B[k][n], n = nt*16+(lane&15), k = ks*32+(lane>>4)*8+j
    for (int t = i; t < 98304; t += stride) {
      int j = t & 7, lane = (t >> 3) & 63, nt = (t >> 9) & 3, ks = (t >> 11) & 1, h = (t >> 12) & 7, sm = t >> 15;
      int k = ks * 32 + (lane >> 4) * 8 + j;
      int n = nt * 16 + (lane & 15);
      const float* W = (sm == 0) ? Wq : ((sm == 1) ? Wk : Wv);
      Wfrag[t] = f2bf(W[(h * 64 + n) * 64 + k]);
    }
    // Pfrag[mt8][ks2][lane][j] : A[m][k], k = ks*32+(lane>>4)*8+j ; k=0 zero pad
    // pi-permuted m: m = (mt>>2)*64 + (r>>2)*16 + (mt&3)*4 + (r&3), r = lane&15 -> phase-2
    // C element (mt, row=q*4+reg) lands at natural semantic byte (mt>>2)*64 + q*16 + (mt&3)*4 + reg.
    for (int t = i; t < 8192; t += stride) {
      int j = t & 7, lane = (t >> 3) & 63, ks = (t >> 9) & 1, mt = (t >> 10) & 7;
      int k = ks * 32 + (lane >> 4) * 8 + j;
      int r = lane & 15;
      int m = ((mt >> 2) << 6) + ((r >> 2) << 4) + ((mt & 3) << 2) + (r & 3);
      Pfrag[t] = (k == 0) ? (unsigned short)0 : f2bf(P[(k - 1) * 128 + m] * (SQRT2F * LOG2E));
    }
  }
}

// ---------------- K2: fused mu -> (q,k,v) -> phi_q, phi_k (fp8) ; + last partial (phik^T @ V) ----------------
// Block = 256 thr (4 waves), block (h, t) owns 128 nodes. LDS 26624 B -> 6 blocks/CU LDS-cap.
// r8 restructure: phase-3 LDS tiles widened to ALL 128 nodes (stride 136):
//   kbuf2 [128 m][136] e4m3 (17408 B) written directly inside phase2(sm=1) after a barrier
//   (each wave's bsf/sbuf reads complete into regs before the barrier), and
//   vbuf2 [64 d][136] e4m3 (8704 B) written directly in phase1(sm=2).
// This deletes the cross-phase registers keepA/keepB (16) + vk (8) -> live set ~80, so
// __launch_bounds__(256,5) caps at 102 regs (safe headroom; r6 showed 64-cap => fatal spill).
// Phase 3 is a single 4-step kc loop, 2 barriers total (was 4).
__global__ __launch_bounds__(256, 5) void k2_mfma(const unsigned short* __restrict__ ubf,
                                                  const unsigned short* __restrict__ Wfrag,
                                                  const unsigned short* __restrict__ Pfrag,
                                                  unsigned char* __restrict__ phiq, unsigned char* __restrict__ phik,
                                                  unsigned char* __restrict__ part8) {
  __shared__ short lds_raw[13312];             // 26624 B
  short* sbuf = lds_raw;                       // phase12: [w*2304 + row*72 + col] bf16 (18432 B)
  float* sfront = (float*)(lds_raw + 13056);   // byte 26112: [w*32 + row] (512 B)
  unsigned char* kbuf2 = (unsigned char*)lds_raw;          // [m*136 + col] e4m3 (17408 B) [aliases sbuf]
  unsigned char* vbuf2 = (unsigned char*)lds_raw + 17408;  // [d*136 + node] e4m3 (8704 B) [aliases sbuf tail]

  int w = threadIdx.x >> 6, lane = threadIdx.x & 63;
  int q = lane >> 4, l = lane & 15;
  int b = blockIdx.x;
  int h = b >> 8, t = b & 255;
  int n0 = t * 128 + w * 32;

  // A-fragments of u (bf16 direct loads)
  s8v afr[2][2];
#pragma unroll
  for (int mt = 0; mt < 2; ++mt)
#pragma unroll
    for (int ks = 0; ks < 2; ++ks)
      afr[mt][ks] = *(const s8v*)(ubf + (size_t)(n0 + mt * 16 + l) * 64 + ks * 32 + q * 8);

  const s8v* Wf = (const s8v*)Wfrag;
  const s8v* Pf = (const s8v*)Pfrag;

  // ---- Interleaved phase 1+2 per sm ----
#pragma unroll
  for (int sm = 0; sm < 3; ++sm) {
    f4v acc[2][4];
#pragma unroll
    for (int mt = 0; mt < 2; ++mt)
#pragma unroll
      for (int nt = 0; nt < 4; ++nt) acc[mt][nt] = (f4v)(0.f);
#pragma unroll
    for (int ks = 0; ks < 2; ++ks)
#pragma unroll
      for (int nt = 0; nt < 4; ++nt) {
        s8v bf = Wf[(((sm * 8 + h) * 2 + ks) * 4 + nt) * 64 + lane];
#pragma unroll
        for (int mt = 0; mt < 2; ++mt)
          acc[mt][nt] = __builtin_amdgcn_mfma_f32_16x16x32_bf16(afr[mt][ks], bf, acc[mt][nt], 0, 0, 0);
      }
#pragma unroll
    for (int mt = 0; mt < 2; ++mt) {
      float rs[4];
#pragma unroll
      for (int reg = 0; reg < 4; ++reg) {
        float v0 = (l == 0) ? 0.f : acc[mt][0][reg];
        rs[reg] = v0 * v0 + acc[mt][1][reg] * acc[mt][1][reg] + acc[mt][2][reg] * acc[mt][2][reg] +
                  acc[mt][3][reg] * acc[mt][3][reg];
      }
#pragma unroll
      for (int reg = 0; reg < 4; ++reg) {
#pragma unroll
        for (int off = 1; off < 16; off <<= 1) rs[reg] += __shfl_xor(rs[reg], off, 64);
      }
      float vreg[4][4];  // [nt][reg], sm==2 only
#pragma unroll
      for (int reg = 0; reg < 4; ++reg) {
        float x = fmaxf(fsqrt(rs[reg]), EPSF);
        float e = fexp2(x * LOG2E);
        float sh = 0.5f * (e - frcp(e));
        float ratio = sh * frcp(x);
        float sh2 = sh * sh;
        int row = mt * 16 + q * 4 + reg;
        if (sm == 2) {
          float tt2 = fsqrt(1.f + sh2);
#pragma unroll
          for (int nt = 0; nt < 4; ++nt) {
            float val = acc[mt][nt][reg] * ratio;
            if (l == 0 && nt == 0) val = tt2;  // time component (d=0)
            vreg[nt][reg] = val;
          }
        } else {
          float lf = -sh2 * LOG2E - LOG2SQRT63;
          if (l == 0) sfront[w * 32 + row] = lf;
#pragma unroll
          for (int nt = 0; nt < 4; ++nt) {
            float val = acc[mt][nt][reg] * ratio;
            if (l == 0 && nt == 0) val = 0.f;
            // write swizzle: col ^ ((q>>1)<<4)  (q>>1 == (row>>3)&1)
            sbuf[w * 2304 + row * 72 + ((nt * 16 + l) ^ ((q >> 1) << 4))] =
                (short)(__float_as_uint(val) >> 16);
          }
        }
      }
      if (sm == 2) {
        // V -> vbuf2 e4m3 directly: node = w*32 + mt*16 + q*4 + reg, d = nt*16 + l
#pragma unroll
        for (int nt = 0; nt < 4; ++nt) {
          unsigned pv = __builtin_amdgcn_cvt_pk_fp8_f32(vreg[nt][0], vreg[nt][1], 0, 0);
          pv = __builtin_amdgcn_cvt_pk_fp8_f32(vreg[nt][2], vreg[nt][3], pv, 1);
          *(unsigned*)&vbuf2[(nt * 16 + l) * 136 + w * 32 + mt * 16 + q * 4] = pv;
        }
      }
    }

    // ---- Phase 2 for this sm (q,k only): phi = exp2(acc + lf) -> fp8 global (+ kbuf2 for sm=1) ----
    if (sm < 2) {
      int fr = (l >> 3) & 1;  // read swizzle: (row>>3)&1 for row = nt2*16 + l
      s8v bsf[2][2];          // [nt2][ks] : B[k=c][n=node]
#pragma unroll
      for (int nt = 0; nt < 2; ++nt)
#pragma unroll
        for (int ks = 0; ks < 2; ++ks)
          bsf[nt][ks] = *(const s8v*)&sbuf[w * 2304 + (nt * 16 + l) * 72 + ((ks * 32 + q * 8) ^ (fr << 4))];
      float lf0 = sfront[w * 32 + l];
      float lf1 = sfront[w * 32 + 16 + l];
      if (sm == 1) __syncthreads();  // all sbuf/sfront reads in regs -> kbuf2/vbuf2 may alias sbuf
      unsigned char* dst = sm ? phik : phiq;
      unsigned g0a[4], g0b[4], g1a[4], g1b[4];
      int c0 = (w * 32 + l) ^ (q << 4), c1 = (w * 32 + 16 + l) ^ (q << 4);  // kbuf2 swizzle: q == (row>>4)&3
#pragma unroll
      for (int mt = 0; mt < 8; ++mt) {
        f4v a0 = (f4v)(0.f), a1 = (f4v)(0.f);
#pragma unroll
        for (int ks = 0; ks < 2; ++ks) {
          s8v ap = Pf[(mt * 2 + ks) * 64 + lane];
          a0 = __builtin_amdgcn_mfma_f32_16x16x32_bf16(ap, bsf[0][ks], a0, 0, 0, 0);
          a1 = __builtin_amdgcn_mfma_f32_16x16x32_bf16(ap, bsf[1][ks], a1, 0, 0, 0);
        }
        float v00 = fexp2(a0[0] + lf0), v01 = fexp2(a0[1] + lf0), v02 = fexp2(a0[2] + lf0), v03 = fexp2(a0[3] + lf0);
        float v10 = fexp2(a1[0] + lf1), v11 = fexp2(a1[1] + lf1), v12 = fexp2(a1[2] + lf1), v13 = fexp2(a1[3] + lf1);
        unsigned p0 = __builtin_amdgcn_cvt_pk_fp8_f32(v00, v01, 0, 0);
        p0 = __builtin_amdgcn_cvt_pk_fp8_f32(v02, v03, p0, 1);
        unsigned p1 = __builtin_amdgcn_cvt_pk_fp8_f32(v10, v11, 0, 0);
        p1 = __builtin_amdgcn_cvt_pk_fp8_f32(v12, v13, p1, 1);
        if (mt < 4) { g0a[mt] = p0; g1a[mt] = p1; }
        else        { g0b[mt - 4] = p0; g1b[mt - 4] = p1; }
        if (sm == 1) {
          // phik bytes -> kbuf2: byte r of p0/p1 holds semantic m = M0+r (pi-permutation)
          int M0 = ((mt >> 2) << 6) + (q << 4) + ((mt & 3) << 2);
#pragma unroll
          for (int r = 0; r < 4; ++r) {
            kbuf2[(M0 + r) * 136 + c0] = (unsigned char)(p0 >> (8 * r));
            kbuf2[(M0 + r) * 136 + c1] = (unsigned char)(p1 >> (8 * r));
          }
        }
      }
      size_t b0 = (size_t)(n0 + l) * 1024 + (size_t)(h * 128 + q * 16);
      *(uint4*)(dst + b0)              = make_uint4(g0a[0], g0a[1], g0a[2], g0a[3]);
      *(uint4*)(dst + b0 + 64)         = make_uint4(g0b[0], g0b[1], g0b[2], g0b[3]);
      *(uint4*)(dst + b0 + 16384)      = make_uint4(g1a[0], g1a[1], g1a[2], g1a[3]);  // node +16
      *(uint4*)(dst + b0 + 16384 + 64) = make_uint4(g1b[0], g1b[1], g1b[2], g1b[3]);
    }
  }

  // ---- Phase 3: single-pass GEMM over all 128 nodes: D[m][d] = sum_node phik[node][m] * V[node][d] ----
  __syncthreads();  // kbuf2 (all waves' phik) + vbuf2 (all waves' V) ready
  f4v facc[2][4];
#pragma unroll
  for (int mtl = 0; mtl < 2; ++mtl)
#pragma unroll
    for (int nt = 0; nt < 4; ++nt) facc[mtl][nt] = (f4v)(0.f);

#pragma unroll
  for (int kc = 0; kc < 4; ++kc) {
    long bv[4];
#pragma unroll
    for (int nt = 0; nt < 4; ++nt)
      bv[nt] = *(const long*)&vbuf2[(nt * 16 + l) * 136 + kc * 32 + q * 8];
    long av[2];
#pragma unroll
    for (int mtl = 0; mtl < 2; ++mtl) {
      int row = (2 * w + mtl) * 16 + l;
      int cb = (kc * 32 + q * 8) ^ (((2 * w + mtl) & 3) << 4);  // read swizzle matches (row>>4)&3
      av[mtl] = *(const long*)&kbuf2[row * 136 + cb];
    }
#pragma unroll
    for (int mtl = 0; mtl < 2; ++mtl)
#pragma unroll
      for (int nt = 0; nt < 4; ++nt)
        facc[mtl][nt] = __builtin_amdgcn_mfma_f32_16x16x32_fp8_fp8(av[mtl], bv[nt], facc[mtl][nt], 0, 0, 0);
  }

  // store part[t][h][d][m] e5m2 fp8, m-contiguous 4B stores
#pragma unroll
  for (int mtl = 0; mtl < 2; ++mtl)
#pragma unroll
    for (int nt = 0; nt < 4; ++nt) {
      unsigned pk8 = __builtin_amdgcn_cvt_pk_bf8_f32(facc[mtl][nt][0], facc[mtl][nt][1], 0, 0);
      pk8 = __builtin_amdgcn_cvt_pk_bf8_f32(facc[mtl][nt][2], facc[mtl][nt][3], pk8, 1);
      int d = nt * 16 + l;
      int m = (2 * w + mtl) * 16 + q * 4;
      *(unsigned*)(part8 + ((size_t)((t * 8 + h) * 64 + d)) * 128 + m) = pk8;
    }
}

// ---------------- K35: fused (blocks<64: reduce fp8 partials -> lastB bf8) + (else: link loss) ----------------
__global__ __launch_bounds__(256) void k35(const unsigned* __restrict__ part32, unsigned char* __restrict__ lastB,
                                           const unsigned char* __restrict__ phiq,
                                           const unsigned char* __restrict__ phik,
                                           const int* __restrict__ ei, float* __restrict__ ea) {
  int b = blockIdx.x;
  if (b < 64) {
    // reduce 256 e5m2 partials -> lastB (bf8 e5m2, B-frag byte order). 4 m-values per thread.
    int t2 = b * 256 + threadIdx.x;  // 16384 = h*2048 + d*32 + mq
    float s0 = 0.f, s1 = 0.f, s2 = 0.f, s3 = 0.f;
#pragma unroll 8
    for (int c = 0; c < 256; ++c) {
      unsigned v = part32[(c << 14) + t2];  // per-c block = 65536 B = 16384 dwords
      f2v lo = __builtin_amdgcn_cvt_pk_f32_bf8(v, 0);
      f2v hi = __builtin_amdgcn_cvt_pk_f32_bf8(v, 1);
      s0 += lo.x; s1 += lo.y; s2 += hi.x; s3 += hi.y;
    }
    int mq = t2 & 31, d = (t2 >> 5) & 63, h = t2 >> 11;
    int m0 = mq * 4;
    int ks = m0 >> 5, j0 = m0 & 7, qq = (m0 >> 3) & 3;
    int lane = qq * 16 + (d & 15), nt = d >> 4;
    unsigned r = __builtin_amdgcn_cvt_pk_bf8_f32(s0, s1, 0, 0);
    r = __builtin_amdgcn_cvt_pk_bf8_f32(s2, s3, r, 1);
    *(unsigned*)(lastB + ((((h * 4 + ks) * 4 + nt) * 64 + lane) << 3) + j0) = r;
    return;
  }
  // link loss: 8 edges per wave, 2-edge batches for load ILP
  __shared__ float part[4];
  int lane = threadIdx.x & 63, w = threadIdx.x >> 6;
  int wid = (b - 64) * 4 + w;  // 8192 waves
  float acc0 = 0.f, acc1 = 0.f;
#pragma unroll
  for (int i = 0; i < 8; i += 2) {
    int e0 = wid * 8 + i, e1 = e0 + 1;
    int s0 = ei[e0], d0 = ei[NEDGES + e0];
    int s1 = ei[e1], d1 = ei[NEDGES + e1];
    uint4 qa = *(const uint4*)(phiq + (size_t)d0 * 1024 + lane * 16);
    uint4 ka = *(const uint4*)(phik + (size_t)s0 * 1024 + lane * 16);
    uint4 qb = *(const uint4*)(phiq + (size_t)d1 * 1024 + lane * 16);
    uint4 kb = *(const uint4*)(phik + (size_t)s1 * 1024 + lane * 16);
    unsigned qs[8] = {qa.x, qa.y, qa.z, qa.w, qb.x, qb.y, qb.z, qb.w};
    unsigned ks[8] = {ka.x, ka.y, ka.z, ka.w, kb.x, kb.y, kb.z, kb.w};
#pragma unroll
    for (int p = 0; p < 8; ++p) {
      f2v q0 = __builtin_amdgcn_cvt_pk_f32_fp8(qs[p], 0);
      f2v q1 = __builtin_amdgcn_cvt_pk_f32_fp8(qs[p], 1);
      f2v k0 = __builtin_amdgcn_cvt_pk_f32_fp8(ks[p], 0);
      f2v k1 = __builtin_amdgcn_cvt_pk_f32_fp8(ks[p], 1);
      float t0 = fmaf(q0.x, k0.x, q0.y * k0.y);
      float t1 = fmaf(q1.x, k1.x, q1.y * k1.y);
      if (p < 4) acc0 += t0 + t1; else acc1 += t0 + t1;
    }
  }
  float acc = acc0 + acc1;
#pragma unroll
  for (int o = 1; o < 64; o <<= 1) acc += __shfl_xor(acc, o, 64);
  if (lane == 0) part[w] = acc;
  __syncthreads();
  if (threadIdx.x == 0) atomicAdd(ea, part[0] + part[1] + part[2] + part[3]);
}

// ---------------- K4: fp8xbf8 MFMA zo = phiq @ last[h'] ; row-norm; 8-head mean; final normalize ----------------
__global__ __launch_bounds__(512) void k4_mfma(const unsigned char* __restrict__ phiq,
                                               const unsigned char* __restrict__ lastB,
                                               const float* __restrict__ ea, float* __restrict__ out) {
  __shared__ unsigned zbufT[8][64][18];
  int w = threadIdx.x >> 6, lane = threadIdx.x & 63;
  int q = lane >> 4, l = lane & 15;
  int n0 = blockIdx.x * 32;

  const long* Bf = (const long*)lastB;
  long bf[4][4];
#pragma unroll
  for (int ks = 0; ks < 4; ++ks)
#pragma unroll
    for (int nt = 0; nt < 4; ++nt) bf[ks][nt] = Bf[((w * 4 + ks) * 4 + nt) * 64 + lane];

  long af[2][4];
#pragma unroll
  for (int mt = 0; mt < 2; ++mt)
#pragma unroll
    for (int ks = 0; ks < 4; ++ks)
      af[mt][ks] = *(const long*)(phiq + (size_t)(8 * (n0 + mt * 16 + l) + w) * 128 + ks * 32 + q * 8);

  f4v acc[2][4];
#pragma unroll
  for (int mt = 0; mt < 2; ++mt)
#pragma unroll
    for (int nt = 0; nt < 4; ++nt) acc[mt][nt] = (f4v)(0.f);
#pragma unroll
  for (int ks = 0; ks < 4; ++ks)
#pragma unroll
    for (int nt = 0; nt < 4; ++nt)
#pragma unroll
      for (int mt = 0; mt < 2; ++mt)
        acc[mt][nt] = __builtin_amdgcn_mfma_f32_16x16x32_fp8_bf8(af[mt][ks], bf[ks][nt], acc[mt][nt], 0, 0, 0);

#pragma unroll
  for (int mt = 0; mt < 2; ++mt) {
    float rs[4];
#pragma unroll
    for (int reg = 0; reg < 4; ++reg) {
      float v0 = acc[mt][0][reg];
      float s0 = (l == 0) ? -v0 * v0 : v0 * v0;
      rs[reg] = s0 + acc[mt][1][reg] * acc[mt][1][reg] + acc[mt][2][reg] * acc[mt][2][reg] +
                acc[mt][3][reg] * acc[mt][3][reg];
    }
#pragma unroll
    for (int reg = 0; reg < 4; ++reg) {
#pragma unroll
      for (int off = 1; off < 16; off <<= 1) rs[reg] += __shfl_xor(rs[reg], off, 64);
    }
    float inv[4];
#pragma unroll
    for (int reg = 0; reg < 4; ++reg) inv[reg] = frcp(fsqrt(fabsf(rs[reg])));
#pragma unroll
    for (int nt = 0; nt < 4; ++nt) {
      uint2 pk;
      pk.x = pack2(acc[mt][nt][0] * inv[0], acc[mt][nt][1] * inv[1]);
      pk.y = pack2(acc[mt][nt][2] * inv[2], acc[mt][nt][3] * inv[3]);
      *(uint2*)&zbufT[w][nt * 16 + l][mt * 8 + q * 2] = pk;
    }
  }
  __syncthreads();

  int tid = threadIdx.x;
  int i = tid >> 4, dg = tid & 15;  // row i 0..31, d-group dg*4..+3
  int i2 = i >> 1, sel = i & 1;
  float s[4] = {0.f, 0.f, 0.f, 0.f};
#pragma unroll
  for (int w2 = 0; w2 < 8; ++w2) {
#pragma unroll
    for (int j = 0; j < 4; ++j) {
      unsigned u = zbufT[w2][dg * 4 + j][i2];
      s[j] += bf2f((unsigned short)(sel ? (u >> 16) : (u & 0xffffu)));
    }
  }
  float m2 = 0.f;
#pragma unroll
  for (int j = 0; j < 4; ++j) {
    s[j] *= 0.125f;
    m2 += ((dg == 0 && j == 0) ? -s[j] * s[j] : s[j] * s[j]);
  }
#pragma unroll
  for (int off = 1; off < 16; off <<= 1) m2 += __shfl_xor(m2, off, 64);
  float inv = frcp(fsqrt(fabsf(m2)));
  float4 o = make_float4(s[0] * inv, s[1] * inv, s[2] * inv, s[3] * inv);
  *(float4*)(out + (size_t)(n0 + i) * 64 + dg * 4) = o;
  if (blockIdx.x == 0 && tid == 0) out[(size_t)NNODES * 64] = ea[0] * (1.0f / 524288.0f);
}

// ---------------- launch ----------------
extern "C" void kernel_launch(void* const* d_in, const int* in_sizes, int n_in,
                              void* d_out, int out_size, void* d_ws, size_t ws_size,
                              hipStream_t stream) {
  const float* z  = (const float*)d_in[0];
  const float* Wq = (const float*)d_in[1];
  const float* Wk = (const float*)d_in[2];
  const float* Wv = (const float*)d_in[3];
  const float* P  = (const float*)d_in[4];
  const int* ei   = (const int*)d_in[5];
  char* ws = (char*)d_ws;
  unsigned short* Wfrag = (unsigned short*)(ws + OFF_WFRAG);
  unsigned char*  lastB = (unsigned char*)(ws + OFF_LASTB);  // sequenced reuse of Wfrag region
  unsigned short* Pfrag = (unsigned short*)(ws + OFF_PFRAG);
  float*          ea    = (float*)(ws + OFF_EA);
  unsigned short* ubf   = (unsigned short*)(ws + OFF_U);
  unsigned char*  part8 = (unsigned char*)(ws + OFF_PART);
  unsigned char*  phiq  = (unsigned char*)(ws + OFF_PHIQ);
  unsigned char*  phik  = (unsigned char*)(ws + OFF_PHIK);

  k01_prep<<<2048, 256, 0, stream>>>(z, ubf, Wq, Wk, Wv, P, Wfrag, Pfrag, ea);
  k2_mfma<<<2048, 256, 0, stream>>>(ubf, Wfrag, Pfrag, phiq, phik, part8);
  k35<<<64 + 2048, 256, 0, stream>>>((const unsigned*)part8, lastB, phiq, phik, ei, ea);
  k4_mfma<<<NNODES / 32, 512, 0, stream>>>(phiq, lastB, ea, (float*)d_out);
}

// Round 9
// 177.068 us; speedup vs baseline: 1.0569x; 1.0569x over previous
//
#include <hip/hip_runtime.h>

#define DEV __device__ __forceinline__

// ---------------- constants ----------------
// N_NODES=32768, N_EDGES=65536, H=8, D=64, DS=63, M=128, R=H*N=262144
#define NNODES 32768
#define NEDGES 65536
#define NROWS  262144
#define EPSF   1e-7f
#define SQRT2F 1.4142135623730951f
#define LOG2E  1.4426950408889634f
#define LOG2SQRT63 2.9886399611087573f   // log2(sqrt(63))

// ---------------- ws layout (bytes) ----------------
#define OFF_WFRAG 0u          // bf16 [3][8][2][4][64][8]  W in MFMA B-frag order (196608 B) [dead after k2]
#define OFF_LASTB 0u          // bf8  [8][4][4][64][8] B-frag of last (65536 B) [written k35, read k4]
#define OFF_PFRAG 196608u     // bf16 [8][2][64][8]  sqrt(2)*log2e*P, A-frag order (pi-permuted m) (16384 B)
#define OFF_EA    212992u     // float [1] (zeroed by k01)
#define OFF_U     409600u     // bf16 [N][64] u (4194304 B) [dead after k2]
#define OFF_PART  42352640u   // bf8 e5m2 [256 c][8 h][64 d][128 m] split-K partials of last (16777216 B)
#define OFF_PHIQ  75907072u   // fp8 e4m3 [n][h][128] (33554432 B)
#define OFF_PHIK  143015936u  // fp8 e4m3 [n][h][128] (33554432 B)

typedef short s8v __attribute__((ext_vector_type(8)));   // 8 bf16 in 4 VGPRs (MFMA A/B frag)
typedef float f4v __attribute__((ext_vector_type(4)));   // MFMA C/D frag
typedef float f2v __attribute__((ext_vector_type(2)));

// ---------------- helpers ----------------
DEV unsigned short f2bf(float f) {  // rne
  unsigned u = __float_as_uint(f);
  return (unsigned short)((u + 0x7fffu + ((u >> 16) & 1u)) >> 16);
}
DEV float bf2f(unsigned short h) { return __uint_as_float(((unsigned)h) << 16); }
// pack two f32 -> two bf16 (round-half-up) in one uint: low short = bf16(lo), high = bf16(hi)
DEV unsigned pack2(float lo, float hi) {
  return __builtin_amdgcn_perm(__float_as_uint(hi) + 0x8000u, __float_as_uint(lo) + 0x8000u, 0x07060302u);
}
DEV float frcp(float x) { return __builtin_amdgcn_rcpf(x); }
DEV float fsqrt(float x) { return __builtin_amdgcn_sqrtf(x); }    // raw v_sqrt_f32, args in normal range
DEV float fexp2(float x) { return __builtin_amdgcn_exp2f(x); }    // raw v_exp_f32, args in normal range

// ---------------- K01: u cast (+ blocks<96: pack W/P frags; block0: zero ea) ----------------
// u = logmap0(proj(expmap0(z))) == [0, z[1:]] identically (acosh(cosh t)=t for t~0.08).
__global__ __launch_bounds__(256) void k01_prep(const float* __restrict__ z, unsigned short* __restrict__ ubf,
                                                const float* __restrict__ Wq, const float* __restrict__ Wk,
                                                const float* __restrict__ Wv, const float* __restrict__ P,
                                                unsigned short* __restrict__ Wfrag, unsigned short* __restrict__ Pfrag,
                                                float* __restrict__ ea) {
  int i = blockIdx.x * 256 + threadIdx.x;  // 524288 float4 groups
  float4 v = *(const float4*)(z + (size_t)i * 4);
  if ((i & 15) == 0) v.x = 0.f;  // time slot
  uint2 pk;
  pk.x = pack2(v.x, v.y);
  pk.y = pack2(v.z, v.w);
  *(uint2*)(ubf + (size_t)i * 4) = pk;

  if (blockIdx.x < 96) {
    if (i == 0) ea[0] = 0.f;
    int stride = 96 * 256;
    // Wfrag[sm][h][ks][nt][lane][j] : B[k][n], n = nt*16+(lane&15), k = ks*32+(lane>>4)*8+j
    for (int t = i; t < 98304; t += stride) {
      int j = t & 7, lane = (t >> 3) & 63, nt = (t >> 9) & 3, ks = (t >> 11) & 1, h = (t >> 12) & 7, sm = t >> 15;
      int k = ks * 32 + (lane >> 4) * 8 + j;
      int n = nt * 16 + (lane & 15);
      const float* W = (sm == 0) ? Wq : ((sm == 1) ? Wk : Wv);
      Wfrag[t] = f2bf(W[(h * 64 + n) * 64 + k]);
    }
    // Pfrag[mt8][ks2][lane][j] : A[m][k], k = ks*32+(lane>>4)*8+j ; k=0 zero pad
    // pi-permuted m: m = (mt>>2)*64 + (r>>2)*16 + (mt&3)*4 + (r&3), r = lane&15 -> phase-2
    // C element (mt, row=q*4+reg) lands at natural semantic byte (mt>>2)*64 + q*16 + (mt&3)*4 + reg.
    for (int t = i; t < 8192; t += stride) {
      int j = t & 7, lane = (t >> 3) & 63, ks = (t >> 9) & 1, mt = (t >> 10) & 7;
      int k = ks * 32 + (lane >> 4) * 8 + j;
      int r = lane & 15;
      int m = ((mt >> 2) << 6) + ((r >> 2) << 4) + ((mt & 3) << 2) + (r & 3);
      Pfrag[t] = (k == 0) ? (unsigned short)0 : f2bf(P[(k - 1) * 128 + m] * (SQRT2F * LOG2E));
    }
  }
}

// ---------------- K2: fused mu -> (q,k,v) -> phi_q, phi_k (fp8) ; + last partial (phik^T @ V) ----------------
// Block = 256 thr (4 waves), block (h, t) owns 128 nodes. LDS 18944 B.
// __launch_bounds__(256,4): 128 unified regs/wave. Register-cap dose-response measured:
//   (256,8)=64-cap  -> fatal spill (FETCH 155MB, WRITE 322MB, 127us)   [r6]
//   (256,5)=102-cap -> mild spill (+25MB scratch, 74.7us @ 43% occ)    [r8]
//   (256,4)=128-cap -> clean (FETCH 10.6MB, 57us @ 31% occ)            [r7]  <- operating point
// The interleaved phase1/2/3 live set genuinely needs ~100+ regs; spill always loses.
// part stored as e5m2 fp8: halves split-K traffic AND improves accuracy (RNE vs pack2's
// round-half-up bias that accumulated coherently over the 256-term reduction; absmax 1.15e-4 -> 6e-6).
__global__ __launch_bounds__(256, 4) void k2_mfma(const unsigned short* __restrict__ ubf,
                                                  const unsigned short* __restrict__ Wfrag,
                                                  const unsigned short* __restrict__ Pfrag,
                                                  unsigned char* __restrict__ phiq, unsigned char* __restrict__ phik,
                                                  unsigned char* __restrict__ part8) {
  __shared__ short lds_raw[9472];              // 18944 B
  short* sbuf = lds_raw;                       // phase12: [w*2304 + row*72 + col] (18432 B)
  float* sfront = (float*)(lds_raw + 9216);    // phase12: [w*32 + row] (512 B)
  unsigned char* kbufT8 = (unsigned char*)lds_raw;         // phase3 alias: [m*72 + col] e4m3 (9216 B)
  unsigned char* vbufT8 = (unsigned char*)lds_raw + 9216;  // phase3 alias: [d*72 + nloc] e4m3 (4608 B)

  int w = threadIdx.x >> 6, lane = threadIdx.x & 63;
  int q = lane >> 4, l = lane & 15;
  int b = blockIdx.x;
  int h = b >> 8, t = b & 255;
  int n0 = t * 128 + w * 32;

  // A-fragments of u (bf16 direct loads)
  s8v afr[2][2];
#pragma unroll
  for (int mt = 0; mt < 2; ++mt)
#pragma unroll
    for (int ks = 0; ks < 2; ++ks)
      afr[mt][ks] = *(const s8v*)(ubf + (size_t)(n0 + mt * 16 + l) * 64 + ks * 32 + q * 8);

  const s8v* Wf = (const s8v*)Wfrag;
  const s8v* Pf = (const s8v*)Pfrag;
  unsigned vk[2][4];           // V e4m3: [mt][nt], 4 nodes per dword
  unsigned keepA[8], keepB[8]; // phik e4m3 store-dwords: [mt] for node n0+l / n0+16+l

  // ---- Interleaved phase 1+2 per sm ----
#pragma unroll
  for (int sm = 0; sm < 3; ++sm) {
    f4v acc[2][4];
#pragma unroll
    for (int mt = 0; mt < 2; ++mt)
#pragma unroll
      for (int nt = 0; nt < 4; ++nt) acc[mt][nt] = (f4v)(0.f);
#pragma unroll
    for (int ks = 0; ks < 2; ++ks)
#pragma unroll
      for (int nt = 0; nt < 4; ++nt) {
        s8v bf = Wf[(((sm * 8 + h) * 2 + ks) * 4 + nt) * 64 + lane];
#pragma unroll
        for (int mt = 0; mt < 2; ++mt)
          acc[mt][nt] = __builtin_amdgcn_mfma_f32_16x16x32_bf16(afr[mt][ks], bf, acc[mt][nt], 0, 0, 0);
      }
#pragma unroll
    for (int mt = 0; mt < 2; ++mt) {
      float rs[4];
#pragma unroll
      for (int reg = 0; reg < 4; ++reg) {
        float v0 = (l == 0) ? 0.f : acc[mt][0][reg];
        rs[reg] = v0 * v0 + acc[mt][1][reg] * acc[mt][1][reg] + acc[mt][2][reg] * acc[mt][2][reg] +
                  acc[mt][3][reg] * acc[mt][3][reg];
      }
#pragma unroll
      for (int reg = 0; reg < 4; ++reg) {
#pragma unroll
        for (int off = 1; off < 16; off <<= 1) rs[reg] += __shfl_xor(rs[reg], off, 64);
      }
      float vreg[4][4];  // [nt][reg], sm==2 only
#pragma unroll
      for (int reg = 0; reg < 4; ++reg) {
        float x = fmaxf(fsqrt(rs[reg]), EPSF);
        float e = fexp2(x * LOG2E);
        float sh = 0.5f * (e - frcp(e));
        float ratio = sh * frcp(x);
        float sh2 = sh * sh;
        int row = mt * 16 + q * 4 + reg;
        if (sm == 2) {
          float tt2 = fsqrt(1.f + sh2);
#pragma unroll
          for (int nt = 0; nt < 4; ++nt) {
            float val = acc[mt][nt][reg] * ratio;
            if (l == 0 && nt == 0) val = tt2;  // time component (d=0)
            vreg[nt][reg] = val;
          }
        } else {
          float lf = -sh2 * LOG2E - LOG2SQRT63;
          if (l == 0) sfront[w * 32 + row] = lf;
#pragma unroll
          for (int nt = 0; nt < 4; ++nt) {
            float val = acc[mt][nt][reg] * ratio;
            if (l == 0 && nt == 0) val = 0.f;
            // write swizzle: col ^ ((q>>1)<<4)  (q>>1 == (row>>3)&1)
            sbuf[w * 2304 + row * 72 + ((nt * 16 + l) ^ ((q >> 1) << 4))] =
                (short)(__float_as_uint(val) >> 16);
          }
        }
      }
      if (sm == 2) {
#pragma unroll
        for (int nt = 0; nt < 4; ++nt) {
          unsigned pv = __builtin_amdgcn_cvt_pk_fp8_f32(vreg[nt][0], vreg[nt][1], 0, 0);
          vk[mt][nt] = __builtin_amdgcn_cvt_pk_fp8_f32(vreg[nt][2], vreg[nt][3], pv, 1);
        }
      }
    }

    // ---- Phase 2 for this sm (q,k only): phi = exp2(acc + lf) -> fp8 global ----
    if (sm < 2) {
      int fr = (l >> 3) & 1;  // read swizzle: (row>>3)&1 for row = nt2*16 + l
      s8v bsf[2][2];          // [nt2][ks] : B[k=c][n=node]
#pragma unroll
      for (int nt = 0; nt < 2; ++nt)
#pragma unroll
        for (int ks = 0; ks < 2; ++ks)
          bsf[nt][ks] = *(const s8v*)&sbuf[w * 2304 + (nt * 16 + l) * 72 + ((ks * 32 + q * 8) ^ (fr << 4))];
      float lf0 = sfront[w * 32 + l];
      float lf1 = sfront[w * 32 + 16 + l];
      unsigned char* dst = sm ? phik : phiq;
      unsigned g0a[4], g0b[4], g1a[4], g1b[4];
#pragma unroll
      for (int mt = 0; mt < 8; ++mt) {
        f4v a0 = (f4v)(0.f), a1 = (f4v)(0.f);
#pragma unroll
        for (int ks = 0; ks < 2; ++ks) {
          s8v ap = Pf[(mt * 2 + ks) * 64 + lane];
          a0 = __builtin_amdgcn_mfma_f32_16x16x32_bf16(ap, bsf[0][ks], a0, 0, 0, 0);
          a1 = __builtin_amdgcn_mfma_f32_16x16x32_bf16(ap, bsf[1][ks], a1, 0, 0, 0);
        }
        float v00 = fexp2(a0[0] + lf0), v01 = fexp2(a0[1] + lf0), v02 = fexp2(a0[2] + lf0), v03 = fexp2(a0[3] + lf0);
        float v10 = fexp2(a1[0] + lf1), v11 = fexp2(a1[1] + lf1), v12 = fexp2(a1[2] + lf1), v13 = fexp2(a1[3] + lf1);
        unsigned p0 = __builtin_amdgcn_cvt_pk_fp8_f32(v00, v01, 0, 0);
        p0 = __builtin_amdgcn_cvt_pk_fp8_f32(v02, v03, p0, 1);
        unsigned p1 = __builtin_amdgcn_cvt_pk_fp8_f32(v10, v11, 0, 0);
        p1 = __builtin_amdgcn_cvt_pk_fp8_f32(v12, v13, p1, 1);
        if (mt < 4) { g0a[mt] = p0; g1a[mt] = p1; }
        else        { g0b[mt - 4] = p0; g1b[mt - 4] = p1; }
        if (sm == 1) { keepA[mt] = p0; keepB[mt] = p1; }
      }
      size_t b0 = (size_t)(n0 + l) * 1024 + (size_t)(h * 128 + q * 16);
      *(uint4*)(dst + b0)              = make_uint4(g0a[0], g0a[1], g0a[2], g0a[3]);
      *(uint4*)(dst + b0 + 64)         = make_uint4(g0b[0], g0b[1], g0b[2], g0b[3]);
      *(uint4*)(dst + b0 + 16384)      = make_uint4(g1a[0], g1a[1], g1a[2], g1a[3]);  // node +16
      *(uint4*)(dst + b0 + 16384 + 64) = make_uint4(g1b[0], g1b[1], g1b[2], g1b[3]);
    }
  }

  // ---- Fused GEMM over two 64-node halves: D[m][d] = sum_node phik[node][m] * V[node][d] ----
  // fp8 x fp8 MFMA: A = phik e4m3 (exact global-store dwords), B = V e4m3.
  f4v facc[2][4];
#pragma unroll
  for (int mtl = 0; mtl < 2; ++mtl)
#pragma unroll
    for (int nt = 0; nt < 4; ++nt) facc[mtl][nt] = (f4v)(0.f);

#pragma unroll
  for (int hf = 0; hf < 2; ++hf) {
    __syncthreads();  // previous contents (sbuf/sfront / prior half) fully consumed
    if ((w >> 1) == hf) {
      int nd0 = (w & 1) * 32 + l, nd1 = nd0 + 16;
      int c0 = nd0 ^ (q << 4), c1 = nd1 ^ (q << 4);  // write swizzle: q == (m>>4)&3
#pragma unroll
      for (int mt = 0; mt < 8; ++mt) {
        // keepA[mt] byte r holds semantic m = M0+r -> kbufT8 row x holds semantic m = x.
        int M0 = ((mt >> 2) << 6) + (q << 4) + ((mt & 3) << 2);
        unsigned a = keepA[mt], bq = keepB[mt];
#pragma unroll
        for (int r = 0; r < 4; ++r) {
          kbufT8[(M0 + r) * 72 + c0] = (unsigned char)(a >> (8 * r));
          kbufT8[(M0 + r) * 72 + c1] = (unsigned char)(bq >> (8 * r));
        }
      }
#pragma unroll
      for (int mt = 0; mt < 2; ++mt)
#pragma unroll
        for (int nt = 0; nt < 4; ++nt)
          *(unsigned*)&vbufT8[(nt * 16 + l) * 72 + (w & 1) * 32 + mt * 16 + q * 4] = vk[mt][nt];
    }
    __syncthreads();  // half ready
#pragma unroll
    for (int kc = 0; kc < 2; ++kc) {
      long bv[4];
#pragma unroll
      for (int nt = 0; nt < 4; ++nt)
        bv[nt] = *(const long*)&vbufT8[(nt * 16 + l) * 72 + kc * 32 + q * 8];
      long av[2];
#pragma unroll
      for (int mtl = 0; mtl < 2; ++mtl) {
        int row = (2 * w + mtl) * 16 + l;
        int cb = (kc * 32 + q * 8) ^ (((2 * w + mtl) & 3) << 4);  // read swizzle matches (m>>4)&3
        av[mtl] = *(const long*)&kbufT8[row * 72 + cb];
      }
#pragma unroll
      for (int mtl = 0; mtl < 2; ++mtl)
#pragma unroll
        for (int nt = 0; nt < 4; ++nt)
          facc[mtl][nt] = __builtin_amdgcn_mfma_f32_16x16x32_fp8_fp8(av[mtl], bv[nt], facc[mtl][nt], 0, 0, 0);
    }
  }

  // store part[t][h][d][m] e5m2 fp8, m-contiguous 4B stores
#pragma unroll
  for (int mtl = 0; mtl < 2; ++mtl)
#pragma unroll
    for (int nt = 0; nt < 4; ++nt) {
      unsigned pk8 = __builtin_amdgcn_cvt_pk_bf8_f32(facc[mtl][nt][0], facc[mtl][nt][1], 0, 0);
      pk8 = __builtin_amdgcn_cvt_pk_bf8_f32(facc[mtl][nt][2], facc[mtl][nt][3], pk8, 1);
      int d = nt * 16 + l;
      int m = (2 * w + mtl) * 16 + q * 4;
      *(unsigned*)(part8 + ((size_t)((t * 8 + h) * 64 + d)) * 128 + m) = pk8;
    }
}

// ---------------- K35: fused (blocks<64: reduce fp8 partials -> lastB bf8) + (else: link loss) ----------------
__global__ __launch_bounds__(256) void k35(const unsigned* __restrict__ part32, unsigned char* __restrict__ lastB,
                                           const unsigned char* __restrict__ phiq,
                                           const unsigned char* __restrict__ phik,
                                           const int* __restrict__ ei, float* __restrict__ ea) {
  int b = blockIdx.x;
  if (b < 64) {
    // reduce 256 e5m2 partials -> lastB (bf8 e5m2, B-frag byte order). 4 m-values per thread.
    int t2 = b * 256 + threadIdx.x;  // 16384 = h*2048 + d*32 + mq
    float s0 = 0.f, s1 = 0.f, s2 = 0.f, s3 = 0.f;
#pragma unroll 8
    for (int c = 0; c < 256; ++c) {
      unsigned v = part32[(c << 14) + t2];  // per-c block = 65536 B = 16384 dwords
      f2v lo = __builtin_amdgcn_cvt_pk_f32_bf8(v, 0);
      f2v hi = __builtin_amdgcn_cvt_pk_f32_bf8(v, 1);
      s0 += lo.x; s1 += lo.y; s2 += hi.x; s3 += hi.y;
    }
    int mq = t2 & 31, d = (t2 >> 5) & 63, h = t2 >> 11;
    int m0 = mq * 4;
    int ks = m0 >> 5, j0 = m0 & 7, qq = (m0 >> 3) & 3;
    int lane = qq * 16 + (d & 15), nt = d >> 4;
    unsigned r = __builtin_amdgcn_cvt_pk_bf8_f32(s0, s1, 0, 0);
    r = __builtin_amdgcn_cvt_pk_bf8_f32(s2, s3, r, 1);
    *(unsigned*)(lastB + ((((h * 4 + ks) * 4 + nt) * 64 + lane) << 3) + j0) = r;
    return;
  }
  // link loss: 8 edges per wave, 2-edge batches for load ILP
  __shared__ float part[4];
  int lane = threadIdx.x & 63, w = threadIdx.x >> 6;
  int wid = (b - 64) * 4 + w;  // 8192 waves
  float acc0 = 0.f, acc1 = 0.f;
#pragma unroll
  for (int i = 0; i < 8; i += 2) {
    int e0 = wid * 8 + i, e1 = e0 + 1;
    int s0 = ei[e0], d0 = ei[NEDGES + e0];
    int s1 = ei[e1], d1 = ei[NEDGES + e1];
    uint4 qa = *(const uint4*)(phiq + (size_t)d0 * 1024 + lane * 16);
    uint4 ka = *(const uint4*)(phik + (size_t)s0 * 1024 + lane * 16);
    uint4 qb = *(const uint4*)(phiq + (size_t)d1 * 1024 + lane * 16);
    uint4 kb = *(const uint4*)(phik + (size_t)s1 * 1024 + lane * 16);
    unsigned qs[8] = {qa.x, qa.y, qa.z, qa.w, qb.x, qb.y, qb.z, qb.w};
    unsigned ks[8] = {ka.x, ka.y, ka.z, ka.w, kb.x, kb.y, kb.z, kb.w};
#pragma unroll
    for (int p = 0; p < 8; ++p) {
      f2v q0 = __builtin_amdgcn_cvt_pk_f32_fp8(qs[p], 0);
      f2v q1 = __builtin_amdgcn_cvt_pk_f32_fp8(qs[p], 1);
      f2v k0 = __builtin_amdgcn_cvt_pk_f32_fp8(ks[p], 0);
      f2v k1 = __builtin_amdgcn_cvt_pk_f32_fp8(ks[p], 1);
      float t0 = fmaf(q0.x, k0.x, q0.y * k0.y);
      float t1 = fmaf(q1.x, k1.x, q1.y * k1.y);
      if (p < 4) acc0 += t0 + t1; else acc1 += t0 + t1;
    }
  }
  float acc = acc0 + acc1;
#pragma unroll
  for (int o = 1; o < 64; o <<= 1) acc += __shfl_xor(acc, o, 64);
  if (lane == 0) part[w] = acc;
  __syncthreads();
  if (threadIdx.x == 0) atomicAdd(ea, part[0] + part[1] + part[2] + part[3]);
}

// ---------------- K4: fp8xbf8 MFMA zo = phiq @ last[h'] ; row-norm; 8-head mean; final normalize ----------------
__global__ __launch_bounds__(512) void k4_mfma(const unsigned char* __restrict__ phiq,
                                               const unsigned char* __restrict__ lastB,
                                               const float* __restrict__ ea, float* __restrict__ out) {
  __shared__ unsigned zbufT[8][64][18];
  int w = threadIdx.x >> 6, lane = threadIdx.x & 63;
  int q = lane >> 4, l = lane & 15;
  int n0 = blockIdx.x * 32;

  const long* Bf = (const long*)lastB;
  long bf[4][4];
#pragma unroll
  for (int ks = 0; ks < 4; ++ks)
#pragma unroll
    for (int nt = 0; nt < 4; ++nt) bf[ks][nt] = Bf[((w * 4 + ks) * 4 + nt) * 64 + lane];

  long af[2][4];
#pragma unroll
  for (int mt = 0; mt < 2; ++mt)
#pragma unroll
    for (int ks = 0; ks < 4; ++ks)
      af[mt][ks] = *(const long*)(phiq + (size_t)(8 * (n0 + mt * 16 + l) + w) * 128 + ks * 32 + q * 8);

  f4v acc[2][4];
#pragma unroll
  for (int mt = 0; mt < 2; ++mt)
#pragma unroll
    for (int nt = 0; nt < 4; ++nt) acc[mt][nt] = (f4v)(0.f);
#pragma unroll
  for (int ks = 0; ks < 4; ++ks)
#pragma unroll
    for (int nt = 0; nt < 4; ++nt)
#pragma unroll
      for (int mt = 0; mt < 2; ++mt)
        acc[mt][nt] = __builtin_amdgcn_mfma_f32_16x16x32_fp8_bf8(af[mt][ks], bf[ks][nt], acc[mt][nt], 0, 0, 0);

#pragma unroll
  for (int mt = 0; mt < 2; ++mt) {
    float rs[4];
#pragma unroll
    for (int reg = 0; reg < 4; ++reg) {
      float v0 = acc[mt][0][reg];
      float s0 = (l == 0) ? -v0 * v0 : v0 * v0;
      rs[reg] = s0 + acc[mt][1][reg] * acc[mt][1][reg] + acc[mt][2][reg] * acc[mt][2][reg] +
                acc[mt][3][reg] * acc[mt][3][reg];
    }
#pragma unroll
    for (int reg = 0; reg < 4; ++reg) {
#pragma unroll
      for (int off = 1; off < 16; off <<= 1) rs[reg] += __shfl_xor(rs[reg], off, 64);
    }
    float inv[4];
#pragma unroll
    for (int reg = 0; reg < 4; ++reg) inv[reg] = frcp(fsqrt(fabsf(rs[reg])));
#pragma unroll
    for (int nt = 0; nt < 4; ++nt) {
      uint2 pk;
      pk.x = pack2(acc[mt][nt][0] * inv[0], acc[mt][nt][1] * inv[1]);
      pk.y = pack2(acc[mt][nt][2] * inv[2], acc[mt][nt][3] * inv[3]);
      *(uint2*)&zbufT[w][nt * 16 + l][mt * 8 + q * 2] = pk;
    }
  }
  __syncthreads();

  int tid = threadIdx.x;
  int i = tid >> 4, dg = tid & 15;  // row i 0..31, d-group dg*4..+3
  int i2 = i >> 1, sel = i & 1;
  float s[4] = {0.f, 0.f, 0.f, 0.f};
#pragma unroll
  for (int w2 = 0; w2 < 8; ++w2) {
#pragma unroll
    for (int j = 0; j < 4; ++j) {
      unsigned u = zbufT[w2][dg * 4 + j][i2];
      s[j] += bf2f((unsigned short)(sel ? (u >> 16) : (u & 0xffffu)));
    }
  }
  float m2 = 0.f;
#pragma unroll
  for (int j = 0; j < 4; ++j) {
    s[j] *= 0.125f;
    m2 += ((dg == 0 && j == 0) ? -s[j] * s[j] : s[j] * s[j]);
  }
#pragma unroll
  for (int off = 1; off < 16; off <<= 1) m2 += __shfl_xor(m2, off, 64);
  float inv = frcp(fsqrt(fabsf(m2)));
  float4 o = make_float4(s[0] * inv, s[1] * inv, s[2] * inv, s[3] * inv);
  *(float4*)(out + (size_t)(n0 + i) * 64 + dg * 4) = o;
  if (blockIdx.x == 0 && tid == 0) out[(size_t)NNODES * 64] = ea[0] * (1.0f / 524288.0f);
}

// ---------------- launch ----------------
extern "C" void kernel_launch(void* const* d_in, const int* in_sizes, int n_in,
                              void* d_out, int out_size, void* d_ws, size_t ws_size,
                              hipStream_t stream) {
  const float* z  = (const float*)d_in[0];
  const float* Wq = (const float*)d_in[1];
  const float* Wk = (const float*)d_in[2];
  const float* Wv = (const float*)d_in[3];
  const float* P  = (const float*)d_in[4];
  const int* ei   = (const int*)d_in[5];
  char* ws = (char*)d_ws;
  unsigned short* Wfrag = (unsigned short*)(ws + OFF_WFRAG);
  unsigned char*  lastB = (unsigned char*)(ws + OFF_LASTB);  // sequenced reuse of Wfrag region
  unsigned short* Pfrag = (unsigned short*)(ws + OFF_PFRAG);
  float*          ea    = (float*)(ws + OFF_EA);
  unsigned short* ubf   = (unsigned short*)(ws + OFF_U);
  unsigned char*  part8 = (unsigned char*)(ws + OFF_PART);
  unsigned char*  phiq  = (unsigned char*)(ws + OFF_PHIQ);
  unsigned char*  phik  = (unsigned char*)(ws + OFF_PHIK);

  k01_prep<<<2048, 256, 0, stream>>>(z, ubf, Wq, Wk, Wv, P, Wfrag, Pfrag, ea);
  k2_mfma<<<2048, 256, 0, stream>>>(ubf, Wfrag, Pfrag, phiq, phik, part8);
  k35<<<64 + 2048, 256, 0, stream>>>((const unsigned*)part8, lastB, phiq, phik, ei, ea);
  k4_mfma<<<NNODES / 32, 512, 0, stream>>>(phiq, lastB, ea, (float*)d_out);
}